// Round 4
// baseline (3799.477 us; speedup 1.0000x reference)
//
#include <hip/hip_runtime.h>
#include <math.h>

// ---------------- constants ----------------
#define DTMEM 0.1f   // DT*TAU_MEM_INV
#define DTSYN 0.2f   // DT*TAU_SYN_INV
#define DTTR  0.02f  // DT*TAU_PRE_INV == DT*TAU_POST_INV

static constexpr int B = 32, T = 32;
static constexpr int HD = 60, H1 = 56, HP = 28, H2 = 24;
static constexpr int LD  = HD*HD;   // 3600
static constexpr int L1N = H1*H1;   // 3136
static constexpr int LP  = HP*HP;   // 784
static constexpr int L2N = H2*H2;   // 576

// float offsets into workspace (all multiples of 4 for float4 access)
static constexpr size_t OW1   = 0;                            // 1500
static constexpr size_t OW2   = OW1 + 1500;                   // 75000
static constexpr size_t OV0   = OW2 + 75000;                  // zero-region start
static constexpr size_t OI0   = OV0   + (size_t)B*30*L1N;
static constexpr size_t OTQ1  = OI0   + (size_t)B*30*L1N;
static constexpr size_t OTP1A = OTQ1  + (size_t)B*30*L1N;     // [B,60,60] ping
static constexpr size_t OTP1B = OTP1A + (size_t)B*LD;         // [B,60,60] pong
static constexpr size_t OZ3   = OTP1B + (size_t)B*LD;         // [B,30,28,28]
static constexpr size_t OTP2  = OZ3   + (size_t)B*30*LP;
static constexpr size_t OV1   = OTP2  + (size_t)B*30*LP;      // [B,100,24,24]
static constexpr size_t OI1   = OV1   + (size_t)B*100*L2N;
static constexpr size_t OTQ2  = OI1   + (size_t)B*100*L2N;
static constexpr size_t OZ4   = OTQ2  + (size_t)B*100*L2N;
static constexpr size_t OP1   = OZ4   + (size_t)B*100*L2N;    // stdp1 partials [30][50][32]
static constexpr size_t OG    = OP1   + 48000;                // [T][3200] per-step spike flags
static constexpr size_t OHH   = OG    + (size_t)T*3200;       // [T][500]
static constexpr size_t OW2P  = OHH   + (size_t)T*500;        // padded w2 [100][30][28] (pad must be 0)
static constexpr size_t OCNZ  = OW2P  + 84000;                // int[960][2]
static constexpr size_t OTOT  = OCNZ  + 1920;

struct DK { float v[25]; };

// ================= K_front: DoG + tp1 + conv1 + LIF0 + tq1 + stdp1-partials
//                   + maxpool + tp2 + cnz flags =================
// grid (8 og, 32 b), block 448 = (oo:4, xh:2, y:56). tid = y*8 + xh*4 + oo.
// State (v0/i0/tq1) prefetched into registers at kernel top so the global
// streams overlap the DoG/conv compute phases (k_front is memory-bound).
__global__ __launch_bounds__(448) void k_front(
        const float* __restrict__ x, const float* __restrict__ b1,
        const float* __restrict__ b2, const float* __restrict__ w1c,
        const float* __restrict__ tp1r, float* __restrict__ tp1w,
        float* __restrict__ v0, float* __restrict__ i0, float* __restrict__ tq1,
        float* __restrict__ z3, float* __restrict__ tp2,
        float* __restrict__ part, int* __restrict__ cnz2, DK dk, int t) {
    __shared__ __attribute__((aligned(16))) float xsh[4096];
    __shared__ __attribute__((aligned(16))) float zsh[3600];   // DoG out (= z ch0)
    __shared__ __attribute__((aligned(16))) float tsh[3600];   // tp1 (updated)
    __shared__ float wd[100];
    __shared__ float red[7*200];
    __shared__ int sflags[8];
    int og = blockIdx.x, b = blockIdx.y, tid = threadIdx.x;
    int oo = tid & 3, xh = (tid >> 2) & 1, y = tid >> 3;
    int o = og*4 + oo, x0 = xh*28;
    bool valid = (o < 30);
    int oc = valid ? o : 29;
    // stage x frame + tp1_old (LDS)
    {
        const float4* xs = (const float4*)(x + ((size_t)t*B + b)*4096);
        const float4* ts = (const float4*)(tp1r + (size_t)b*LD);
        float4* xd = (float4*)xsh; float4* td = (float4*)tsh;
        for (int i = tid; i < 1024; i += 448) xd[i] = xs[i];
        for (int i = tid; i < 900; i += 448) td[i] = ts[i];
    }
    // prefetch per-thread LIF/trace state into registers (independent of LDS)
    size_t n0 = ((size_t)(b*30 + oc)*H1 + y)*H1 + x0;
    float4 pv[7], pi4[7], pt4[7];
    #pragma unroll
    for (int i = 0; i < 7; i++) {
        pv[i]  = ((const float4*)(v0 + n0))[i];
        pi4[i] = ((const float4*)(i0 + n0))[i];
        pt4[i] = ((const float4*)(tq1 + n0))[i];
    }
    if (tid < 100) {
        int oo2 = tid / 25, p = tid % 25;
        int o2 = og*4 + oo2; if (o2 > 29) o2 = 29;
        wd[tid] = w1c[o2*50 + p] - w1c[o2*50 + 25 + p];
    }
    if (tid < 8) sflags[tid] = 0;
    __syncthreads();
    float bias = b1[0] - b2[0];
    // DoG + tp1 trace update (in LDS; og==0 persists tp1 to pong buffer)
    for (int idx = tid; idx < 3600; idx += 448) {
        int yy = idx / 60, xx2 = idx % 60;
        float a = 0.f;
        #pragma unroll
        for (int kh = 0; kh < 5; kh++)
            #pragma unroll
            for (int kw = 0; kw < 5; kw++)
                a = fmaf(dk.v[kh*5+kw], xsh[(yy+kh)*64 + xx2 + kw], a);
        float zv = a + bias;
        zsh[idx] = zv;
        float tp = tsh[idx];
        tp = tp + DTTR*(zv - tp);
        tsh[idx] = tp;
        if (og == 0) tp1w[(size_t)b*LD + idx] = tp;
    }
    __syncthreads();
    float accp[25], accm[25];
    #pragma unroll
    for (int p = 0; p < 25; p++) { accp[p] = 0.f; accm[p] = 0.f; }
    bool anym = false;
    if (valid) {
        // conv1 (collapsed on/off channel)
        float acc[28];
        #pragma unroll
        for (int xq = 0; xq < 28; xq++) acc[xq] = 0.f;
        #pragma unroll
        for (int kh = 0; kh < 5; kh++) {
            float rr[32];
            const float4* r4 = (const float4*)&zsh[(y+kh)*HD + x0];
            #pragma unroll
            for (int i = 0; i < 8; i++) ((float4*)rr)[i] = r4[i];
            #pragma unroll
            for (int kw = 0; kw < 5; kw++) {
                float w = wd[oo*25 + kh*5 + kw];
                #pragma unroll
                for (int xq = 0; xq < 28; xq++) acc[xq] = fmaf(w, rr[xq+kw], acc[xq]);
            }
        }
        // LIF0 + tq1 epilogue from prefetched state; keep zn + tn in regs
        float zn[28], tn[28];
        #pragma unroll
        for (int i = 0; i < 7; i++) {
            float4 vn, in, tn4;
            float* vp=(float*)&pv[i]; float* cp=(float*)&pi4[i]; float* tp=(float*)&pt4[i];
            float* vnp=(float*)&vn; float* inp=(float*)&in; float* tnp=(float*)&tn4;
            #pragma unroll
            for (int k = 0; k < 4; k++) {
                float vd = vp[k] + DTMEM*(cp[k] - vp[k]);
                float z = (vd > 15.0f) ? 1.0f : 0.0f;
                vnp[k] = (1.0f - z)*vd;
                inp[k] = (cp[k] - DTSYN*cp[k]) + acc[i*4+k];
                float tq = tp[k] + DTTR*(z - tp[k]);
                tnp[k] = tq;
                zn[i*4+k] = z; tn[i*4+k] = tq;
            }
            ((float4*)(v0 + n0))[i] = vn;
            ((float4*)(i0 + n0))[i] = in;
            ((float4*)(tq1 + n0))[i] = tn4;
        }
        // stdp1 partial correlations (sparsity-gated, exact)
        float zs = 0.f, qs = 0.f;
        #pragma unroll
        for (int xq = 0; xq < 28; xq++) { zs += zn[xq]; qs += tn[xq]; }
        if (qs != 0.f) {   // accm: unfold(z0) x tq1_new
            #pragma unroll
            for (int kh = 0; kh < 5; kh++) {
                float rr[32];
                const float4* r4 = (const float4*)&zsh[(y+kh)*HD + x0];
                #pragma unroll
                for (int i = 0; i < 8; i++) ((float4*)rr)[i] = r4[i];
                #pragma unroll
                for (int kw = 0; kw < 5; kw++)
                    #pragma unroll
                    for (int xq = 0; xq < 28; xq++)
                        accm[kh*5+kw] = fmaf(rr[xq+kw], tn[xq], accm[kh*5+kw]);
            }
        }
        if (zs != 0.f) {   // accp: unfold(tp1_new) x z2
            #pragma unroll
            for (int kh = 0; kh < 5; kh++) {
                float rr[32];
                const float4* r4 = (const float4*)&tsh[(y+kh)*HD + x0];
                #pragma unroll
                for (int i = 0; i < 8; i++) ((float4*)rr)[i] = r4[i];
                #pragma unroll
                for (int kw = 0; kw < 5; kw++)
                    #pragma unroll
                    for (int xq = 0; xq < 28; xq++)
                        accp[kh*5+kw] = fmaf(rr[xq+kw], zn[xq], accp[kh*5+kw]);
            }
        }
        // 2x2 maxpool via shuffle with y-partner (tid^8), + tp2 trace (float2)
        float mx[14];
        #pragma unroll
        for (int k = 0; k < 14; k++) mx[k] = fmaxf(zn[2*k], zn[2*k+1]);
        #pragma unroll
        for (int k = 0; k < 14; k++) {
            float pm = __shfl_xor(mx[k], 8, 64);
            mx[k] = fmaxf(mx[k], pm);
        }
        if ((y & 1) == 0) {
            int py = y >> 1;
            size_t pb = ((size_t)(b*30 + o)*HP + py)*HP + xh*14;
            #pragma unroll
            for (int k = 0; k < 7; k++) {
                float2 m2 = make_float2(mx[2*k], mx[2*k+1]);
                anym = anym || (m2.x != 0.f) || (m2.y != 0.f);
                ((float2*)(z3 + pb))[k] = m2;
                float2 tpv = ((const float2*)(tp2 + pb))[k];
                tpv.x = tpv.x + DTTR*(m2.x - tpv.x);
                tpv.y = tpv.y + DTTR*(m2.y - tpv.y);
                ((float2*)(tp2 + pb))[k] = tpv;
            }
        }
    }
    if (anym) atomicOr(&sflags[oo*2 + xh], 1);
    // deterministic partial reduction (butterfly over xh + 3 y bits, then LDS)
    int lane = tid & 63, wave = tid >> 6;
    #pragma unroll
    for (int q = 0; q < 50; q++) {
        float v = (q < 25) ? accp[q] : accm[q-25];
        v += __shfl_xor(v, 4, 64);
        v += __shfl_xor(v, 8, 64);
        v += __shfl_xor(v, 16, 64);
        v += __shfl_xor(v, 32, 64);
        if (lane < 4) red[wave*200 + lane*50 + q] = v;
    }
    __syncthreads();
    if (tid < 200) {
        int oo2 = tid / 50, q = tid % 50;
        float s = 0.f;
        #pragma unroll
        for (int w = 0; w < 7; w++) s += red[w*200 + oo2*50 + q];
        int o2 = og*4 + oo2;
        if (o2 < 30) part[((size_t)(o2*50 + q) << 5) + b] = s;
    }
    if (tid < 8) {
        int o2 = og*4 + (tid >> 1);
        if (o2 < 30) cnz2[(b*30 + o2)*2 + (tid & 1)] = sflags[tid];
    }
}

// ================= K_B: conv2 (jb=2, dbuf LDS staging) + LIF1 + tq2 + g =================
// grid (13 jg, 32 b), block 192 = (jp:4, xh:2, y:24)
__global__ __launch_bounds__(192) void k_conv2lif(
        const float* __restrict__ w2p, const float* __restrict__ z3,
        const int* __restrict__ cnz2,
        float* __restrict__ v1, float* __restrict__ i1,
        float* __restrict__ z4, float* __restrict__ tq2, float* __restrict__ g_t) {
    __shared__ __attribute__((aligned(16))) float4 sbuf[2][196];
    __shared__ int sact[30];
    __shared__ int sjany[8];
    int jg = blockIdx.x, b = blockIdx.y, tid = threadIdx.x;
    int jb0 = jg*8;
    if (tid < 30) sact[tid] = cnz2[(b*30 + tid)*2] | cnz2[(b*30 + tid)*2 + 1];
    if (tid < 8) sjany[tid] = 0;
    int jp = tid & 3, xh = (tid >> 2) & 1, y = tid >> 3;
    int j0 = jb0 + jp*2, x0 = xh*12;
    int ja = (j0 < 100) ? j0 : 99;        // clamped addr for loads; stores guarded
    int jbb = (j0+1 < 100) ? j0+1 : 99;
    float acc0[12], acc1[12];
    #pragma unroll
    for (int xq = 0; xq < 12; xq++) { acc0[xq] = 0.f; acc1[xq] = 0.f; }
    // stage c=0
    {
        const float4* src = (const float4*)(z3 + (size_t)(b*30)*LP);
        for (int i = tid; i < 196; i += 192) sbuf[0][i] = src[i];
    }
    __syncthreads();
    #pragma unroll 1
    for (int c = 0; c < 30; c++) {
        const float* cur = (const float*)sbuf[c & 1];
        if (c + 1 < 30) {
            const float4* src = (const float4*)(z3 + (size_t)(b*30 + c + 1)*LP);
            float4* nxt = sbuf[(c + 1) & 1];
            for (int i = tid; i < 196; i += 192) nxt[i] = src[i];
        }
        if (sact[c]) {
            float wa[28], wb[28];
            #pragma unroll
            for (int i = 0; i < 7; i++) {
                ((float4*)wa)[i] = ((const float4*)(w2p + ((size_t)ja*30 + c)*28))[i];
                ((float4*)wb)[i] = ((const float4*)(w2p + ((size_t)jbb*30 + c)*28))[i];
            }
            #pragma unroll
            for (int kh = 0; kh < 5; kh++) {
                float rr[16];
                const float4* r4 = (const float4*)&cur[(y+kh)*HP + x0];
                #pragma unroll
                for (int i = 0; i < 4; i++) ((float4*)rr)[i] = r4[i];
                #pragma unroll
                for (int kw = 0; kw < 5; kw++) {
                    float w0 = wa[kh*5+kw], w1 = wb[kh*5+kw];
                    #pragma unroll
                    for (int xq = 0; xq < 12; xq++) {
                        acc0[xq] = fmaf(w0, rr[xq+kw], acc0[xq]);
                        acc1[xq] = fmaf(w1, rr[xq+kw], acc1[xq]);
                    }
                }
            }
        }
        __syncthreads();
    }
    bool spk0 = false, spk1 = false;
    #pragma unroll
    for (int jj = 0; jj < 2; jj++) {
        int j = j0 + jj;
        if (j < 100) {
            size_t n0 = ((size_t)(b*100 + j)*H2 + y)*H2 + x0;
            bool anyspk = false;
            #pragma unroll
            for (int i = 0; i < 3; i++) {
                float4 v4 = ((const float4*)(v1 + n0))[i];
                float4 c4 = ((const float4*)(i1 + n0))[i];
                float4 t4 = ((const float4*)(tq2 + n0))[i];
                float4 vn, in, zn, tn;
                float* vp=(float*)&v4; float* cp=(float*)&c4; float* tp=(float*)&t4;
                float* vnp=(float*)&vn; float* inp=(float*)&in; float* znp=(float*)&zn; float* tnp=(float*)&tn;
                #pragma unroll
                for (int k = 0; k < 4; k++) {
                    float a = jj ? acc1[i*4+k] : acc0[i*4+k];
                    float vd = vp[k] + DTMEM*(cp[k] - vp[k]);
                    float z = (vd > 10.0f) ? 1.0f : 0.0f;
                    vnp[k] = (1.0f - z)*vd;
                    inp[k] = (cp[k] - DTSYN*cp[k]) + 10.0f*a;
                    znp[k] = z;
                    tnp[k] = tp[k] + DTTR*(z - tp[k]);
                    anyspk = anyspk || (z != 0.f);
                }
                ((float4*)(v1 + n0))[i] = vn;
                ((float4*)(i1 + n0))[i] = in;
                ((float4*)(z4 + n0))[i] = zn;
                ((float4*)(tq2 + n0))[i] = tn;
            }
            if (jj == 0) spk0 = anyspk; else spk1 = anyspk;
        }
    }
    if (spk0) atomicOr(&sjany[jp*2], 1);
    if (spk1) atomicOr(&sjany[jp*2+1], 1);
    __syncthreads();
    if (tid < 8 && jb0 + tid < 100) g_t[b*100 + jb0 + tid] = sjany[tid] ? 1.f : 0.f;
}

// ================= K_C: fused stdp2 correlations (both modes) + w2 apply + w1 apply ===========
// grid (13 jg, 31 c), block 192 = (jp:4, xh:2, y:24). c==30 row: jg==0 does w1 apply.
// mode0 (E+): pre=tp2, post=z4, per-b gate = g flags (per j-pair).
// mode1 (E-): pre=z3,  post=tq2, per-b gate = cnz (uniform).
__global__ __launch_bounds__(192) void k_corr2(
        const float* __restrict__ tp2, const float* __restrict__ z3,
        const float* __restrict__ z4, const float* __restrict__ tq2,
        const float* __restrict__ g_t, const int* __restrict__ cnz2,
        float* __restrict__ w2c, float* __restrict__ w2p,
        float* __restrict__ w1c, const float* __restrict__ part) {
    int jg = blockIdx.x, c = blockIdx.y, tid = threadIdx.x;
    if (c == 30) {
        if (jg != 0) return;
        for (int e = tid; e < 1500; e += 192) {
            int o = e / 50, r = e % 50, ch = r / 25, p = r % 25;
            float EpS = 0.f, EmS = 0.f;
            #pragma unroll
            for (int s = 0; s < 32; s++) {
                EpS += part[((size_t)(o*50 + p) << 5) + s];
                EmS += part[((size_t)(o*50 + 25 + p) << 5) + s];
            }
            float sign = (ch == 0) ? 1.0f : -1.0f;
            float w = w1c[e];
            float dwp = 0.004f * fmaxf(1.0f - w, 0.0f) * (sign * EpS);
            float dwm = 0.003f * fmaxf(w, 0.0f) * (sign * EmS);
            w1c[e] = fminf(fmaxf(w + dwp - dwm, 0.0f), 1.0f);
        }
        return;
    }
    __shared__ __attribute__((aligned(16))) float4 sb[2][2][196];  // [phase][0=tp2,1=z3]
    __shared__ int sact1[32];
    __shared__ float red[3*400];
    int jb0 = jg*8;
    int jp = tid & 3, xh = (tid >> 2) & 1, y = tid >> 3;
    int j0 = jb0 + jp*2, x0 = xh*12;
    int jl0 = (j0 < 100) ? j0 : 99;
    int jl1 = (j0+1 < 100) ? j0+1 : 99;
    if (tid < 32) sact1[tid] = cnz2[(tid*30 + c)*2] | cnz2[(tid*30 + c)*2 + 1];
    float A0[25], A1[25], M0[25], M1[25];
    #pragma unroll
    for (int p = 0; p < 25; p++) { A0[p] = 0.f; A1[p] = 0.f; M0[p] = 0.f; M1[p] = 0.f; }
    // stage b=0 (both pre arrays)
    {
        const float4* s0 = (const float4*)(tp2 + (size_t)c*LP);
        const float4* s1 = (const float4*)(z3 + (size_t)c*LP);
        for (int i = tid; i < 196; i += 192) { sb[0][0][i] = s0[i]; sb[0][1][i] = s1[i]; }
    }
    __syncthreads();
    #pragma unroll 1
    for (int b = 0; b < B; b++) {
        const float* curP = (const float*)sb[b & 1][0];
        const float* curM = (const float*)sb[b & 1][1];
        if (b + 1 < B) {
            const float4* s0 = (const float4*)(tp2 + (size_t)((b+1)*30 + c)*LP);
            const float4* s1 = (const float4*)(z3 + (size_t)((b+1)*30 + c)*LP);
            float4* d0 = sb[(b+1) & 1][0]; float4* d1 = sb[(b+1) & 1][1];
            for (int i = tid; i < 196; i += 192) { d0[i] = s0[i]; d1[i] = s1[i]; }
        }
        float gA = g_t[b*100 + jl0], gB = g_t[b*100 + jl1];
        bool do0 = (gA != 0.f) || (gB != 0.f);
        bool do1 = sact1[b] != 0;
        if (do0 || do1) {
            float pA[12], pB[12], qA[12], qB[12];
            if (do0) {
                size_t nA = ((size_t)(b*100 + jl0)*H2 + y)*H2 + x0;
                size_t nB = ((size_t)(b*100 + jl1)*H2 + y)*H2 + x0;
                #pragma unroll
                for (int i = 0; i < 3; i++) {
                    ((float4*)pA)[i] = ((const float4*)(z4 + nA))[i];
                    ((float4*)pB)[i] = ((const float4*)(z4 + nB))[i];
                }
            }
            if (do1) {
                size_t nA = ((size_t)(b*100 + jl0)*H2 + y)*H2 + x0;
                size_t nB = ((size_t)(b*100 + jl1)*H2 + y)*H2 + x0;
                #pragma unroll
                for (int i = 0; i < 3; i++) {
                    ((float4*)qA)[i] = ((const float4*)(tq2 + nA))[i];
                    ((float4*)qB)[i] = ((const float4*)(tq2 + nB))[i];
                }
            }
            #pragma unroll
            for (int kh = 0; kh < 5; kh++) {
                float rrP[16], rrM[16];
                const float4* r4P = (const float4*)&curP[(y+kh)*HP + x0];
                const float4* r4M = (const float4*)&curM[(y+kh)*HP + x0];
                if (do0) {
                    #pragma unroll
                    for (int i = 0; i < 4; i++) ((float4*)rrP)[i] = r4P[i];
                }
                if (do1) {
                    #pragma unroll
                    for (int i = 0; i < 4; i++) ((float4*)rrM)[i] = r4M[i];
                }
                #pragma unroll
                for (int kw = 0; kw < 5; kw++) {
                    if (do0) {
                        #pragma unroll
                        for (int xq = 0; xq < 12; xq++) {
                            A0[kh*5+kw] = fmaf(rrP[xq+kw], pA[xq], A0[kh*5+kw]);
                            A1[kh*5+kw] = fmaf(rrP[xq+kw], pB[xq], A1[kh*5+kw]);
                        }
                    }
                    if (do1) {
                        #pragma unroll
                        for (int xq = 0; xq < 12; xq++) {
                            M0[kh*5+kw] = fmaf(rrM[xq+kw], qA[xq], M0[kh*5+kw]);
                            M1[kh*5+kw] = fmaf(rrM[xq+kw], qB[xq], M1[kh*5+kw]);
                        }
                    }
                }
            }
        }
        __syncthreads();
    }
    int lane = tid & 63, wave = tid >> 6;
    #pragma unroll
    for (int q = 0; q < 100; q++) {
        float v = (q < 25) ? A0[q] : (q < 50) ? A1[q-25] : (q < 75) ? M0[q-50] : M1[q-75];
        v += __shfl_xor(v, 4, 64);
        v += __shfl_xor(v, 8, 64);
        v += __shfl_xor(v, 16, 64);
        v += __shfl_xor(v, 32, 64);
        if (lane < 4) red[wave*400 + lane*100 + q] = v;
    }
    __syncthreads();
    if (tid < 200) {
        int jp2 = tid / 50, q = tid % 50;
        float Ep = red[0*400 + jp2*100 + q] + red[1*400 + jp2*100 + q] + red[2*400 + jp2*100 + q];
        float Em = red[0*400 + jp2*100 + 50 + q] + red[1*400 + jp2*100 + 50 + q] + red[2*400 + jp2*100 + 50 + q];
        int j = jb0 + jp2*2 + ((q < 25) ? 0 : 1), p = q % 25;
        if (j < 100) {
            size_t f = (size_t)j*750 + (size_t)c*25 + p;
            float w = w2c[f];
            float dwp = 0.004f * fmaxf(1.0f - w, 0.0f) * Ep;
            float dwm = 0.003f * fmaxf(w, 0.0f) * Em;
            float wn = fminf(fmaxf(w + dwp - dwm, 0.0f), 1.0f);
            w2c[f] = wn;
            w2p[((size_t)j*30 + c)*28 + p] = wn;
        }
    }
}

// ================= k_prep: build padded w2p from initial w2 (pad pre-zeroed) ===========
__global__ void k_prep(const float* __restrict__ w2, float* __restrict__ w2p) {
    int e = blockIdx.x*blockDim.x + threadIdx.x;
    if (e < 75000) {
        int j = e / 750, r = e % 750, c = r / 25, p = r % 25;
        w2p[((size_t)j*30 + c)*28 + p] = w2[e];
    }
}

// ================= k_fc1b: batched fc1 over all T (fcw read once) =================
__global__ __launch_bounds__(256) void k_fc1b(
        const float* __restrict__ g_all, const float* __restrict__ fcw,
        const float* __restrict__ fcb, float* __restrict__ h_all) {
    __shared__ float red[32][4];
    int n = blockIdx.x, tid = threadIdx.x;
    const float4* w4 = (const float4*)(fcw + (size_t)n*3200);
    float4 wreg[4];
    #pragma unroll
    for (int i = 0; i < 4; i++) {
        int k = tid + 256*i;
        if (k < 800) wreg[i] = w4[k];
    }
    float accs[32];
    #pragma unroll
    for (int t = 0; t < 32; t++) accs[t] = 0.f;
    #pragma unroll 1
    for (int t = 0; t < 32; t++) {
        const float4* g4 = (const float4*)(g_all + (size_t)t*3200);
        float a = 0.f;
        #pragma unroll
        for (int i = 0; i < 4; i++) {
            int k = tid + 256*i;
            if (k < 800) {
                float4 gv = g4[k];
                a = fmaf(gv.x, wreg[i].x, a);
                a = fmaf(gv.y, wreg[i].y, a);
                a = fmaf(gv.z, wreg[i].z, a);
                a = fmaf(gv.w, wreg[i].w, a);
            }
        }
        accs[t] = a;
    }
    int lane = tid & 63, wid = tid >> 6;
    #pragma unroll
    for (int t = 0; t < 32; t++) {
        float v = accs[t];
        #pragma unroll
        for (int s = 32; s >= 1; s >>= 1) v += __shfl_down(v, s, 64);
        if (lane == 0) red[t][wid] = v;
    }
    __syncthreads();
    if (tid < 32)
        h_all[(size_t)tid*500 + n] = red[tid][0] + red[tid][1] + red[tid][2] + red[tid][3] + fcb[n];
}

// ================= k_head_all: LIF2 + LI readout, all T in one block =================
__global__ __launch_bounds__(640) void k_head_all(
        const float* __restrict__ h_all, const float* __restrict__ outw,
        float* __restrict__ out) {
    __shared__ float spk[500];
    __shared__ float vout[10];
    int tid = threadIdx.x;
    int wid = tid >> 6, lane = tid & 63;
    float v2r = 0.f, i2r = 0.f;
    float vor = 0.f, ior = 0.f;
    #pragma unroll 1
    for (int t = 0; t < 32; t++) {
        if (tid < 500) {
            float cur = i2r;
            float vd = v2r + DTMEM*(cur - v2r);
            float z = (vd > 1.0f) ? 1.0f : 0.0f;
            v2r = (1.0f - z)*vd;
            i2r = (cur - DTSYN*cur) + h_all[t*500 + tid];
            spk[tid] = z;
        }
        __syncthreads();
        float acc = 0.f;
        for (int n = lane; n < 500; n += 64)
            acc = fmaf(spk[n], outw[wid*500 + n], acc);
        #pragma unroll
        for (int s = 32; s >= 1; s >>= 1) acc += __shfl_down(acc, s, 64);
        if (lane == 0) {
            float ij = ior + acc;
            float vn = vor + DTMEM*(ij - vor);
            ior = ij - DTSYN*ij;
            vor = vn;
            vout[wid] = vn;
        }
        __syncthreads();
        if (tid < 320) out[(size_t)t*320 + tid] = vout[tid % 10];
        __syncthreads();
    }
}

// ---------------- launcher ----------------
extern "C" void kernel_launch(void* const* d_in, const int* in_sizes, int n_in,
                              void* d_out, int out_size, void* d_ws, size_t ws_size,
                              hipStream_t stream) {
    const float* x    = (const float*)d_in[0];
    const float* b1   = (const float*)d_in[1];
    const float* b2   = (const float*)d_in[2];
    const float* w1   = (const float*)d_in[3];
    const float* w2   = (const float*)d_in[4];
    const float* fcw  = (const float*)d_in[5];
    const float* fcb  = (const float*)d_in[6];
    const float* outw = (const float*)d_in[7];
    float* ws  = (float*)d_ws;
    float* out = (float*)d_out;

    DK dk;
    {
        float g1[25], g2[25], s1 = 0.f, s2 = 0.f;
        for (int i = 0; i < 5; i++)
            for (int j = 0; j < 5; j++) {
                float ai = (float)(i - 2), aj = (float)(j - 2);
                float r2 = ai*ai + aj*aj;
                g1[i*5+j] = expf(-r2/2.0f);
                g2[i*5+j] = expf(-r2/8.0f);
                s1 += g1[i*5+j]; s2 += g2[i*5+j];
            }
        for (int k = 0; k < 25; k++) dk.v[k] = g1[k]/s1 - g2[k]/s2;
    }

    hipMemcpyAsync(ws + OW1, w1, 1500*sizeof(float), hipMemcpyDeviceToDevice, stream);
    hipMemcpyAsync(ws + OW2, w2, 75000*sizeof(float), hipMemcpyDeviceToDevice, stream);
    hipMemsetAsync(ws + OV0, 0, (OTOT - OV0)*sizeof(float), stream);
    k_prep<<<294, 256, 0, stream>>>(ws + OW2, ws + OW2P);

    for (int t = 0; t < T; t++) {
        const float* tp1r = ws + ((t & 1) ? OTP1B : OTP1A);
        float*       tp1w = ws + ((t & 1) ? OTP1A : OTP1B);
        k_front<<<dim3(8, 32), 448, 0, stream>>>(
            x, b1, b2, ws+OW1, tp1r, tp1w, ws+OV0, ws+OI0, ws+OTQ1,
            ws+OZ3, ws+OTP2, ws+OP1, (int*)(ws+OCNZ), dk, t);
        k_conv2lif<<<dim3(13, 32), 192, 0, stream>>>(
            ws+OW2P, ws+OZ3, (int*)(ws+OCNZ),
            ws+OV1, ws+OI1, ws+OZ4, ws+OTQ2, ws+OG + (size_t)t*3200);
        k_corr2<<<dim3(13, 31), 192, 0, stream>>>(
            ws+OTP2, ws+OZ3, ws+OZ4, ws+OTQ2, ws+OG + (size_t)t*3200,
            (int*)(ws+OCNZ), ws+OW2, ws+OW2P, ws+OW1, ws+OP1);
    }
    k_fc1b<<<500, 256, 0, stream>>>(ws+OG, fcw, fcb, ws+OHH);
    k_head_all<<<1, 640, 0, stream>>>(ws+OHH, outw, out);
}